// Round 3
// baseline (9108.246 us; speedup 1.0000x reference)
//
#include <hip/hip_runtime.h>
#include <stdint.h>

#define S_LEN 512
#define NB    64
#define HID   256
#define G3    768
#define SB    32768   // S_LEN * NB
#define NLAYER 6

typedef short bf16x8 __attribute__((ext_vector_type(8)));
typedef float floatx4 __attribute__((ext_vector_type(4)));
typedef unsigned short u16;
typedef unsigned int   u32;

__device__ __forceinline__ float bf2f(u16 v) {
  u32 u = ((u32)v) << 16;
  return __builtin_bit_cast(float, u);
}
__device__ __forceinline__ u16 f2bf(float f) {
  u32 u = __builtin_bit_cast(u32, f);
  u = (u + 0x7FFFu + ((u >> 16) & 1u)) >> 16;
  return (u16)u;
}
__device__ __forceinline__ float fsigmoid(float x) {
  return __builtin_amdgcn_rcpf(1.0f + __expf(-x));
}
__device__ __forceinline__ float ftanh(float x) {
  return 1.0f - 2.0f * __builtin_amdgcn_rcpf(1.0f + __expf(x + x));
}

// ---------------------------------------------------------------------------
// detect_fp32: sample x as u16; count bf16 NaN/Inf exponent patterns.
// fp32 buffer -> low mantissa halves hit exp==0xFF ~0.39% (~500 in sample).
// genuine bf16 normals -> exactly 0. Flag = 1 means inputs are fp32.
// ---------------------------------------------------------------------------
__global__ void detect_fp32(const u16* __restrict__ x, int n, int* flag) {
  __shared__ int tot;
  if (threadIdx.x == 0) tot = 0;
  __syncthreads();
  int c = 0;
  for (int i = threadIdx.x; i < n; i += blockDim.x) {
    u16 v = x[i];
    if (((v >> 7) & 0xFF) == 0xFF) ++c;
  }
  atomicAdd(&tot, c);
  __syncthreads();
  if (threadIdx.x == 0) *flag = (tot > 64) ? 1 : 0;
}

// cvt: input (fp32 or bf16 per flag) -> packed bf16 copy in ws.
__global__ void cvt(const void* __restrict__ src, u16* __restrict__ dst,
                    int n, const int* __restrict__ flag) {
  const int stride = gridDim.x * blockDim.x;
  const bool isf32 = (*flag != 0);
  for (int i = blockIdx.x * blockDim.x + threadIdx.x; i < n; i += stride) {
    if (isf32) dst[i] = f2bf(((const float*)src)[i]);
    else       dst[i] = ((const u16*)src)[i];
  }
}

// write_out: fp32 staging -> d_out in the harness's output dtype per flag.
__global__ void write_out(const float* __restrict__ hNs, void* __restrict__ out,
                          int n, const int* __restrict__ flag) {
  int i = blockIdx.x * blockDim.x + threadIdx.x;
  if (i >= n) return;
  if (*flag) ((float*)out)[i] = hNs[i];
  else       ((u16*)out)[i]   = f2bf(hNs[i]);
}

// ---------------------------------------------------------------------------
// gate_gemm: out[dir][m][n] = sum_k A[m][k] * W[dir][n][k] + bias[dir][n]
// A: [SB][K] bf16 row-major. W: [2][768][K] bf16. out: [2][SB][768] bf16.
// 128x128 tile / WG, BK=64. Register-staged LDS, XOR-swizzled 16B chunks.
// ---------------------------------------------------------------------------
__global__ __launch_bounds__(256)
void gate_gemm(const u16* __restrict__ A, const u16* __restrict__ W,
               const u16* __restrict__ bias, u16* __restrict__ outg, int K) {
  const int m0  = blockIdx.x * 128;
  const int n0  = blockIdx.y * 128;
  const int dir = blockIdx.z;
  W    += (size_t)dir * G3 * K;
  bias += (size_t)dir * G3;
  outg += (size_t)dir * (size_t)SB * G3;

  __shared__ __align__(16) u16 lA[8192];   // 128 rows x 64 k, chunk-swizzled
  __shared__ __align__(16) u16 lB[8192];

  const int tid  = threadIdx.x;
  const int lane = tid & 63;
  const int wv   = tid >> 6;
  const int wm   = wv & 1, wn = wv >> 1;
  const int l15  = lane & 15, quad = lane >> 4;

  floatx4 acc[4][4] = {};   // [mt][nt]

  for (int k0 = 0; k0 < K; k0 += 64) {
    bf16x8 ra[4], rb[4];
#pragma unroll
    for (int i = 0; i < 4; ++i) {
      int c   = i * 256 + tid;          // chunk 0..1023
      int row = c >> 3;
      int kc  = (c & 7) ^ (row & 7);    // XOR-swizzled source chunk
      ra[i] = *(const bf16x8*)(A + (size_t)(m0 + row) * K + (k0 + kc * 8));
      rb[i] = *(const bf16x8*)(W + (size_t)(n0 + row) * K + (k0 + kc * 8));
    }
    __syncthreads();   // previous tile's LDS reads complete
#pragma unroll
    for (int i = 0; i < 4; ++i) {
      *(bf16x8*)(lA + (size_t)(i * 256 + tid) * 8) = ra[i];
      *(bf16x8*)(lB + (size_t)(i * 256 + tid) * 8) = rb[i];
    }
    __syncthreads();

#pragma unroll
    for (int kt = 0; kt < 2; ++kt) {
      bf16x8 af[4], bfr[4];
#pragma unroll
      for (int mt = 0; mt < 4; ++mt) {
        int row = wm * 64 + mt * 16 + l15;
        int ch  = row * 8 + ((kt * 4 + quad) ^ (row & 7));
        af[mt] = *(const bf16x8*)(lA + ch * 8);
      }
#pragma unroll
      for (int nt = 0; nt < 4; ++nt) {
        int row = wn * 64 + nt * 16 + l15;
        int ch  = row * 8 + ((kt * 4 + quad) ^ (row & 7));
        bfr[nt] = *(const bf16x8*)(lB + ch * 8);
      }
#pragma unroll
      for (int mt = 0; mt < 4; ++mt)
#pragma unroll
        for (int nt = 0; nt < 4; ++nt)
          acc[mt][nt] = __builtin_amdgcn_mfma_f32_16x16x32_bf16(
              af[mt], bfr[nt], acc[mt][nt], 0, 0, 0);
    }
  }
  __syncthreads();

  // epilogue: C/D layout col(n)=lane&15, row(m)=quad*4+reg
#pragma unroll
  for (int nt = 0; nt < 4; ++nt) {
    int n    = n0 + wn * 64 + nt * 16 + l15;
    float bv = bf2f(bias[n]);
#pragma unroll
    for (int mt = 0; mt < 4; ++mt) {
#pragma unroll
      for (int r = 0; r < 4; ++r) {
        int m = m0 + wm * 64 + mt * 16 + quad * 4 + r;
        outg[(size_t)m * G3 + n] = f2bf(acc[mt][nt][r] + bv);
      }
    }
  }
}

// ---------------------------------------------------------------------------
// gru_scan: sequential recurrence for one layer, both directions.
// grid = 8 WGs: blockIdx.x = dir + 2*batch_group (4 groups of 16 batch rows).
// 512 threads = 8 waves. W_hh stationary in VGPRs (192 regs/thread bf16).
// ---------------------------------------------------------------------------
__global__ __launch_bounds__(512, 2)
void gru_scan(const u16* __restrict__ gateX,   // [2][SB][768] bf16
              const u16* __restrict__ Whh,     // [2][768][256] (this layer)
              const u16* __restrict__ Bhh,     // [2][768]
              const u16* __restrict__ H0,      // [12][64][256] bf16 copy
              u16* __restrict__ layerOut,      // [SB][512] bf16
              float* __restrict__ hNs,         // fp32 staging [12][64][256]
              int layer) {
  const int dir = blockIdx.x & 1;
  const int bg  = blockIdx.x >> 1;
  const int tid = threadIdx.x;
  const int lane = tid & 63;
  const int wv   = tid >> 6;           // 0..7, owns N-rows [wv*96, wv*96+96)
  const int l15  = lane & 15, quad = lane >> 4;

  __shared__ __align__(16) float gLds[16][772];  // gate preacts [m][768] (+4 pad)
  __shared__ __align__(16) u16   hLds[16][264];  // h bf16, +8 pad per row

  // stationary W_hh fragments (B-operand layout: n=lane&15, k=quad*8+j)
  const u16* Wd = Whh + (size_t)dir * G3 * HID;
  bf16x8 wfr[8][6];                    // [kt][nt]
#pragma unroll
  for (int nt = 0; nt < 6; ++nt) {
    int n = wv * 96 + nt * 16 + l15;
#pragma unroll
    for (int kt = 0; kt < 8; ++kt) {
      int k = kt * 32 + quad * 8;
      wfr[kt][nt] = *(const bf16x8*)(Wd + (size_t)n * HID + k);
    }
  }
  float bh[6];
#pragma unroll
  for (int nt = 0; nt < 6; ++nt)
    bh[nt] = bf2f(Bhh[dir * G3 + wv * 96 + nt * 16 + l15]);

  // gate-phase ownership: gm=tid&15 (batch row), gj=(tid>>4)*8 (H-slice)
  const int gm = tid & 15;
  const int gj = (tid >> 4) * 8;
  const int b_global = bg * 16 + gm;

  float hreg[8];
  {
    const u16* hp = H0 + ((size_t)(layer * 2 + dir) * NB + b_global) * HID + gj;
#pragma unroll
    for (int i = 0; i < 8; ++i) hreg[i] = bf2f(hp[i]);
    bf16x8 hb;
#pragma unroll
    for (int i = 0; i < 8; ++i) hb[i] = (short)f2bf(hreg[i]);
    *(bf16x8*)(&hLds[gm][gj]) = hb;
  }
  __syncthreads();

  const size_t dbase = (size_t)dir * SB * G3;

  for (int t = 0; t < S_LEN; ++t) {
    const int s = dir ? (S_LEN - 1 - t) : t;

    // prefetch x-gates for this step (consumed after the MFMA phase)
    const u16* xp = gateX + dbase + ((size_t)s * NB + b_global) * G3 + gj;
    bf16x8 xr = *(const bf16x8*)(xp);
    bf16x8 xz = *(const bf16x8*)(xp + 256);
    bf16x8 xn = *(const bf16x8*)(xp + 512);

    // MFMA phase: gates_pre = h @ Whh^T + b_hh for this wave's N-slice
    floatx4 acc[6];
#pragma unroll
    for (int nt = 0; nt < 6; ++nt) {
      floatx4 v = {bh[nt], bh[nt], bh[nt], bh[nt]};
      acc[nt] = v;
    }
#pragma unroll
    for (int kt = 0; kt < 8; ++kt) {
      bf16x8 af = *(const bf16x8*)(&hLds[l15][kt * 32 + quad * 8]);
#pragma unroll
      for (int nt = 0; nt < 6; ++nt)
        acc[nt] = __builtin_amdgcn_mfma_f32_16x16x32_bf16(af, wfr[kt][nt],
                                                          acc[nt], 0, 0, 0);
    }
#pragma unroll
    for (int nt = 0; nt < 6; ++nt) {
      int n = wv * 96 + nt * 16 + l15;
#pragma unroll
      for (int r = 0; r < 4; ++r)
        gLds[quad * 4 + r][n] = acc[nt][r];
    }
    __syncthreads();

    // gate phase: 8 h-elements per thread
    const float* grow = &gLds[gm][0];
    float ghr[8], ghz[8], ghn[8];
    *(floatx4*)&ghr[0] = *(const floatx4*)(grow + gj);
    *(floatx4*)&ghr[4] = *(const floatx4*)(grow + gj + 4);
    *(floatx4*)&ghz[0] = *(const floatx4*)(grow + 256 + gj);
    *(floatx4*)&ghz[4] = *(const floatx4*)(grow + 256 + gj + 4);
    *(floatx4*)&ghn[0] = *(const floatx4*)(grow + 512 + gj);
    *(floatx4*)&ghn[4] = *(const floatx4*)(grow + 512 + gj + 4);

    bf16x8 hb;
#pragma unroll
    for (int i = 0; i < 8; ++i) {
      float xrf = bf2f((u16)xr[i]);
      float xzf = bf2f((u16)xz[i]);
      float xnf = bf2f((u16)xn[i]);
      float rg = fsigmoid(xrf + ghr[i]);
      float zg = fsigmoid(xzf + ghz[i]);
      float ng = ftanh(xnf + rg * ghn[i]);
      hreg[i] = (1.0f - zg) * ng + zg * hreg[i];
      hb[i] = (short)f2bf(hreg[i]);
    }
    *(bf16x8*)(&hLds[gm][gj]) = hb;
    *(bf16x8*)(layerOut + ((size_t)s * NB + b_global) * 512 + dir * HID + gj) = hb;
    if (t == S_LEN - 1) {
      float* dst = hNs + ((size_t)(layer * 2 + dir) * NB + b_global) * HID + gj;
      floatx4 v0 = {hreg[0], hreg[1], hreg[2], hreg[3]};
      floatx4 v1 = {hreg[4], hreg[5], hreg[6], hreg[7]};
      *(floatx4*)dst = v0;
      *((floatx4*)dst + 1) = v1;
    }
    __syncthreads();
  }
}

// ---------------------------------------------------------------------------
extern "C" void kernel_launch(void* const* d_in, const int* in_sizes, int n_in,
                              void* d_out, int out_size, void* d_ws, size_t ws_size,
                              hipStream_t stream) {
  (void)n_in; (void)ws_size;
  char* ws = (char*)d_ws;
  // ws layout (176 MiB total):
  //   [0, 4K)        flag
  //   [4K, 1M)       hNs fp32 staging (786432 B)
  //   [1M, 16M)      bf16 copies: h0, wih0, wih, whh, bih, bhh (~12.8 MiB)
  //   [16M, 112M)    gateX bf16 [2][SB][768]
  //   [112M, 144M)   bufA bf16 [SB][512]
  //   [144M, 176M)   bufB bf16 [SB][512]  (xC aliases: consumed layer 0 only)
  int*   flag  = (int*)ws;
  float* hNs   = (float*)(ws + 4096);
  u16*   h0C   = (u16*)(ws + (1u << 20));
  u16*   wih0C = h0C   + 196608;
  u16*   wihC  = wih0C + 196608;
  u16*   whhC  = wihC  + 3932160;
  u16*   bihC  = whhC  + 2359296;
  u16*   bhhC  = bihC  + 9216;
  u16*   gateX = (u16*)(ws + (16u  << 20));
  u16*   bufA  = (u16*)(ws + (112u << 20));
  u16*   bufB  = (u16*)(ws + (144u << 20));
  u16*   xC    = bufB;   // aliased; layer-0 gemm reads it before bufB written

  detect_fp32<<<1, 1024, 0, stream>>>((const u16*)d_in[0], 262144, flag);
  cvt<<<512, 256, 0, stream>>>(d_in[0], xC,    in_sizes[0], flag);
  cvt<<<256, 256, 0, stream>>>(d_in[1], h0C,   in_sizes[1], flag);
  cvt<<<256, 256, 0, stream>>>(d_in[2], wih0C, in_sizes[2], flag);
  cvt<<<512, 256, 0, stream>>>(d_in[3], wihC,  in_sizes[3], flag);
  cvt<<<512, 256, 0, stream>>>(d_in[4], whhC,  in_sizes[4], flag);
  cvt<<< 64, 256, 0, stream>>>(d_in[5], bihC,  in_sizes[5], flag);
  cvt<<< 64, 256, 0, stream>>>(d_in[6], bhhC,  in_sizes[6], flag);

  for (int layer = 0; layer < NLAYER; ++layer) {
    const u16* inp = (layer == 0) ? xC : ((layer & 1) ? bufA : bufB);
    u16* outBuf    = (layer & 1) ? bufB : bufA;

    const int K = (layer == 0) ? 128 : 512;
    const u16* W = (layer == 0) ? wih0C
                                : (wihC + (size_t)(layer - 1) * 2 * G3 * 512);
    dim3 grid(256, 6, 2);
    gate_gemm<<<grid, 256, 0, stream>>>(inp, W, bihC + (size_t)layer * 2 * G3,
                                        gateX, K);
    gru_scan<<<8, 512, 0, stream>>>(gateX, whhC + (size_t)layer * 2 * G3 * HID,
                                    bhhC + (size_t)layer * 2 * G3, h0C,
                                    outBuf, hNs, layer);
  }
  write_out<<<(out_size + 255) / 256, 256, 0, stream>>>(hNs, d_out, out_size, flag);
}